// Round 12
// baseline (237.651 us; speedup 1.0000x reference)
//
#include <hip/hip_runtime.h>

typedef short bf16x8_t __attribute__((ext_vector_type(8)));
typedef float f32x4_t  __attribute__((ext_vector_type(4)));
typedef float f32x16_t __attribute__((ext_vector_type(16)));

#define MFMA16(a,b,c) __builtin_amdgcn_mfma_f32_16x16x32_bf16(a,b,c,0,0,0)
#define MFMA32(a,b,c) __builtin_amdgcn_mfma_f32_32x32x16_bf16(a,b,c,0,0,0)
#define CVTPK(lo, hi, dst) asm("v_cvt_pk_bf16_f32 %0, %1, %2" : "=v"(dst) : "v"(lo), "v"(hi))
#define SWAP32(x, y) asm volatile("v_permlane32_swap_b32 %0, %1" : "+v"(x), "+v"(y))

// pack 8 f32 (t-interleaved 32x32 D-layout) into one bf16x8 A/B-fragment:
// dwords [own01, own23, partner01, partner23] via 2 permlane32_swap
#define PACKFRAG(V, off, dst) do{                                   \
    unsigned a0_, a1_, b0_, b1_;                                    \
    CVTPK(V[(off)+0], V[(off)+1], a0_);                             \
    CVTPK(V[(off)+2], V[(off)+3], a1_);                             \
    CVTPK(V[(off)+4], V[(off)+5], b0_);                             \
    CVTPK(V[(off)+6], V[(off)+7], b1_);                             \
    SWAP32(a0_, b0_);  SWAP32(a1_, b1_);                            \
    union{ unsigned u[4]; bf16x8_t v; } t_;                         \
    t_.u[0] = a0_; t_.u[1] = a1_; t_.u[2] = b0_; t_.u[3] = b1_;     \
    dst = t_.v;                                                     \
  }while(0)

__device__ __forceinline__ unsigned short f2b(float x){
  unsigned u = __float_as_uint(x);
  u += 0x7fffu + ((u >> 16) & 1u);
  return (unsigned short)(u >> 16);
}

__device__ __forceinline__ void bar_lgkm(){
  asm volatile("s_waitcnt lgkmcnt(0)" ::: "memory");
  __builtin_amdgcn_s_barrier();
  __builtin_amdgcn_sched_barrier(0);
}

// ---------------- setup: weights -> bf16 (blocks 0..255) + n_real (blocks 256..383) ----------------
__global__ void setup_k(const float* __restrict__ kw, const float* __restrict__ vw,
                        const int* __restrict__ mask,
                        unsigned short* __restrict__ wktb, unsigned short* __restrict__ wvb,
                        int* __restrict__ nreal){
  int bid = blockIdx.x, tid = threadIdx.x;
  if (bid < 256){
    int i = bid * 256 + tid;                       // 0..65535
    int d = i >> 8, e = i & 255;
    wktb[i] = f2b(kw[e * 256 + d]);                // WkT[d][e] (transposed, for calc_qkp)
    wvb[i]  = f2b(vw[i]);                          // value_w as-is (for vproj_norm)
  } else {
    int b = (bid - 256) * 4 + (tid >> 6), l = tid & 63;
    int s_ = 0;
    #pragma unroll
    for (int j = 0; j < 8; ++j) s_ += mask[(size_t)b * 512 + j * 64 + l];
    #pragma unroll
    for (int k = 1; k < 64; k <<= 1) s_ += __shfl_xor(s_, k);
    if (l == 0) nreal[b] = s_ < 1 ? 1 : (s_ > 512 ? 512 : s_);
  }
}

// ---------------- zero out(acc) + denom ----------------
__global__ void zero_k(float4* __restrict__ acc4, float4* __restrict__ den4){
  int i = blockIdx.x * 256 + threadIdx.x;
  float4 z = {0.f, 0.f, 0.f, 0.f};
  acc4[i] = z;                 // grid covers exactly 1048576 float4 (= d_out)
  if (i < 4096) den4[i] = z;
}

// ---------------- qs[b*32+q][e] = (queries[q,e] + context[b]@cond_w[q*256+e] + cond_b)*scale*inv_t ----------------
__global__ __launch_bounds__(256) void calc_qs(
    const float* __restrict__ context, const float* __restrict__ queries,
    const float* __restrict__ logt, const float* __restrict__ condw,
    const float* __restrict__ condb, unsigned short* __restrict__ qs){
  __shared__ float ctx_l[64 * 64];
  int tid = threadIdx.x;
  int q   = blockIdx.x & 31;
  int b0  = (blockIdx.x >> 5) * 64;
  int qd  = q * 256 + tid;
  float4 cw[16];
  #pragma unroll
  for (int j = 0; j < 16; ++j) cw[j] = *(const float4*)(condw + (size_t)qd * 64 + 4 * j);
  float qbias = queries[qd] + condb[qd];
  float sc = 0.0625f * __expf(-logt[q >> 2]);      // scale * inv_temperature
  #pragma unroll
  for (int j = 0; j < 16; ++j){
    int f = j * 256 + tid;
    ctx_l[f] = context[(size_t)b0 * 64 + f];
  }
  __syncthreads();
  for (int b = 0; b < 64; ++b){
    const float4* cl = (const float4*)(ctx_l + b * 64);
    float acc = 0.f;
    #pragma unroll
    for (int j = 0; j < 16; ++j){
      float4 cv = cl[j]; float4 w4 = cw[j];
      acc += cv.x * w4.x + cv.y * w4.y + cv.z * w4.z + cv.w * w4.w;
    }
    qs[((size_t)(b0 + b) * 32 + q) * 256 + tid] = f2b((qbias + acc) * sc);
  }
}

// ---------------- qkp[row][d] = sum_e qs[row][e] * key_w[e][d]   (row = b*32+q) ----------------
__global__ __launch_bounds__(256) void calc_qkp(
    const unsigned short* __restrict__ qs, const unsigned short* __restrict__ wkt,
    unsigned short* __restrict__ qkp){
  __shared__ unsigned short at[64 * 256];
  int tid = threadIdx.x, w = tid >> 6, l = tid & 63, h = l >> 4, c = l & 15;
  size_t r0 = (size_t)blockIdx.x * 64;
  #pragma unroll
  for (int j = 0; j < 8; ++j){
    int f = j * 256 + tid;
    int row = f >> 5, col = (f & 31) * 8;
    bf16x8_t v = *(const bf16x8_t*)(qs + (r0 + row) * 256 + col);
    *(bf16x8_t*)&at[row * 256 + (col ^ ((row & 7) << 3))] = v;
  }
  __syncthreads();
  f32x4_t zero4 = {0.f, 0.f, 0.f, 0.f};
  f32x4_t acc[4][4];
  #pragma unroll
  for (int mt = 0; mt < 4; ++mt)
    #pragma unroll
    for (int nt = 0; nt < 4; ++nt) acc[mt][nt] = zero4;
  #pragma unroll
  for (int kk = 0; kk < 8; ++kk){
    bf16x8_t A[4];
    #pragma unroll
    for (int mt = 0; mt < 4; ++mt){
      int row = c + 16 * mt;
      A[mt] = *(const bf16x8_t*)&at[row * 256 + ((kk * 32 + 8 * h) ^ ((row & 7) << 3))];
    }
    #pragma unroll
    for (int nt = 0; nt < 4; ++nt){
      int d = 64 * w + 16 * nt + c;
      bf16x8_t Bv = *(const bf16x8_t*)(wkt + (size_t)d * 256 + kk * 32 + 8 * h);
      #pragma unroll
      for (int mt = 0; mt < 4; ++mt) acc[mt][nt] = MFMA16(A[mt], Bv, acc[mt][nt]);
    }
  }
  #pragma unroll
  for (int mt = 0; mt < 4; ++mt)
    #pragma unroll
    for (int nt = 0; nt < 4; ++nt)
      #pragma unroll
      for (int i = 0; i < 4; ++i){
        size_t row = r0 + 16 * mt + 4 * h + i;
        int d = 64 * w + 16 * nt + c;
        qkp[row * 256 + d] = f2b(acc[mt][nt][i]);
      }
}

// ---------------- partial attention, 32x32-MFMA lane-local P design ----------------
// One block per (batch, 256-pos chunk). Per 32-row tile: ONE lgkm-only barrier.
// Each wave computes full 32x32 logits (redundant), softmax in-lane, P->A-frag and
// K^T->B-frag via cvt_pk + v_permlane32_swap (no Pl/vT LDS, no second barrier).
__global__ __launch_bounds__(256, 3) void attn_part(
    const float* __restrict__ keys, const int* __restrict__ nreal,
    const unsigned short* __restrict__ qkp,
    float* __restrict__ acc, float* __restrict__ deng){
  __shared__ unsigned short Kd[2][32 * 256];  // bf16 keys, double-buffered, swizzled (32 KB)
  __shared__ unsigned short qkl[32 * 256];    // qkp rows for this b, swizzled (16 KB)

  int bid = blockIdx.x;
  int b = bid >> 1, ch = bid & 1;
  int n_real = nreal[b];
  int sbase = ch * 256;
  if (sbase >= n_real) return;                 // uniform early-exit, before any barrier

  int tid = threadIdx.x, w = tid >> 6, l = tid & 63;
  int lq = l & 31, hh = l >> 5;

  // stage qkp[b] -> qkl (full-spread swizzle (row&31)<<3, conflict-free b128 reads)
  #pragma unroll
  for (int j = 0; j < 4; ++j){
    int f = j * 2048 + tid * 8;
    int row = f >> 8, col = f & 255;
    bf16x8_t v = *(const bf16x8_t*)(qkp + ((size_t)b * 32 + row) * 256 + col);
    *(bf16x8_t*)&qkl[row * 256 + (col ^ ((row & 31) << 3))] = v;
  }

  // prologue: load tile 0 into registers (rows t = 4j+w, cols 4l..4l+3)
  const float* kptr = keys + ((size_t)b * 512 + sbase + w) * 256 + 4 * l;
  float4 R[8];
  #pragma unroll
  for (int j = 0; j < 8; ++j) R[j] = *(const float4*)(kptr + j * 1024);

  // identity B-fragments for 32x32 transpose: I0[k][n]=d(n=k), I16[k][n]=d(n=k+16)
  bf16x8_t bI0, bI16;
  #pragma unroll
  for (int j = 0; j < 8; ++j){
    bI0[j]  = (j == lq - 8 * hh)      ? (short)0x3F80 : (short)0;
    bI16[j] = (j == lq - 16 - 8 * hh) ? (short)0x3F80 : (short)0;
  }

  float slope0 = exp2f(-2.0f * (float)((lq & 3) + 1));   // head = q&3

  f32x16_t ao0, ao1;
  #pragma unroll
  for (int i = 0; i < 16; ++i){ ao0[i] = 0.f; ao1[i] = 0.f; }
  float dvq = 0.f;

  int tend = (n_real - sbase + 31) >> 5; if (tend > 8) tend = 8;
  int sw = lq << 3;          // swizzle for row lq
  int rbase = lq * 256;

  __syncthreads();           // qkl visible (one-time; vmcnt drain harmless in prologue)

  for (int it = 0; it < tend; ++it){
    int cur = it & 1;
    int s0 = sbase + it * 32;

    // ---- convert R (tile it) -> Kd[cur]; then issue loads for tile it+1 ----
    #pragma unroll
    for (int j = 0; j < 8; ++j){
      int row = 4 * j + w;
      int d4 = 4 * l;
      float4 kv = R[j];
      uint2 p;
      CVTPK(kv.x, kv.y, p.x);
      CVTPK(kv.z, kv.w, p.y);
      *(uint2*)&Kd[cur][row * 256 + (d4 ^ ((row & 31) << 3))] = p;
    }
    if (it + 1 < tend){
      const float* knext = kptr + (size_t)(it + 1) * (32 * 256);
      #pragma unroll
      for (int j = 0; j < 8; ++j) R[j] = *(const float4*)(knext + j * 1024);
    }
    bar_lgkm();              // single barrier per tile: Kd[cur] visible; loads stay in flight

    // ---- logits: S[t][q] = sum_e K[t][e] * qkp[q][e], 16 MFMAs, 2 accumulators ----
    f32x16_t Sa, Sb;
    #pragma unroll
    for (int i = 0; i < 16; ++i){ Sa[i] = 0.f; Sb[i] = 0.f; }
    #pragma unroll
    for (int kk = 0; kk < 16; kk += 2){
      bf16x8_t A0 = *(const bf16x8_t*)&Kd[cur][rbase + ((16 * kk + 8 * hh) ^ sw)];
      bf16x8_t B0 = *(const bf16x8_t*)&qkl[rbase + ((16 * kk + 8 * hh) ^ sw)];
      bf16x8_t A1 = *(const bf16x8_t*)&Kd[cur][rbase + ((16 * kk + 16 + 8 * hh) ^ sw)];
      bf16x8_t B1 = *(const bf16x8_t*)&qkl[rbase + ((16 * kk + 16 + 8 * hh) ^ sw)];
      Sa = MFMA32(A0, B0, Sa);
      Sb = MFMA32(A1, B1, Sb);
    }

    // ---- K^T for own e-range via identity MFMA: D0 -> e[64w,64w+32), D1 -> +32 ----
    f32x16_t D0, D1;
    #pragma unroll
    for (int i = 0; i < 16; ++i){ D0[i] = 0.f; D1[i] = 0.f; }
    {
      bf16x8_t T0 = *(const bf16x8_t*)&Kd[cur][rbase + ((16 * (4 * w + 0) + 8 * hh) ^ sw)];
      bf16x8_t T1 = *(const bf16x8_t*)&Kd[cur][rbase + ((16 * (4 * w + 1) + 8 * hh) ^ sw)];
      bf16x8_t T2 = *(const bf16x8_t*)&Kd[cur][rbase + ((16 * (4 * w + 2) + 8 * hh) ^ sw)];
      bf16x8_t T3 = *(const bf16x8_t*)&Kd[cur][rbase + ((16 * (4 * w + 3) + 8 * hh) ^ sw)];
      D0 = MFMA32(T0, bI0, D0);  D0 = MFMA32(T1, bI16, D0);
      D1 = MFMA32(T2, bI0, D1);  D1 = MFMA32(T3, bI16, D1);
    }

    // ---- softmax in-lane (q = lq, 16 t-values, t=(i&3)+8*(i>>2)+4*hh) ----
    float P[16];
    float fb = (float)(n_real - 1 - s0);
    #pragma unroll
    for (int i = 0; i < 16; ++i){
      int t = (i & 3) + 8 * (i >> 2) + 4 * hh;
      float sv = Sa[i] + Sb[i];
      bool valid = (s0 + t) < n_real;
      float pv = valid ? __expf(sv - slope0 * (fb - (float)t)) : 0.f;
      P[i] = pv;
      dvq += pv;
    }

    // ---- P -> PV A-frags; D0/D1 -> PV B-frags (cvt_pk + permlane32_swap) ----
    bf16x8_t Af0, Af1, Bf00, Bf01, Bf10, Bf11;
    PACKFRAG(P,  0, Af0);   PACKFRAG(P,  8, Af1);
    PACKFRAG(D0, 0, Bf00);  PACKFRAG(D0, 8, Bf01);
    PACKFRAG(D1, 0, Bf10);  PACKFRAG(D1, 8, Bf11);

    // ---- PV: out[q][e] += P[q][t] * K[t][e] ----
    ao0 = MFMA32(Af0, Bf00, ao0);
    ao0 = MFMA32(Af1, Bf01, ao0);
    ao1 = MFMA32(Af0, Bf10, ao1);
    ao1 = MFMA32(Af1, Bf11, ao1);
  }

  // ---- accumulate numerators (atomics into d_out) + denominators ----
  #pragma unroll
  for (int i = 0; i < 16; ++i){
    int q = (i & 3) + 8 * (i >> 2) + 4 * hh;
    atomicAdd(&acc[((size_t)b * 32 + q) * 256 + 64 * w + lq], ao0[i]);
    atomicAdd(&acc[((size_t)b * 32 + q) * 256 + 64 * w + 32 + lq], ao1[i]);
  }
  dvq += __shfl_xor(dvq, 32);
  if (w == 0 && hh == 0) atomicAdd(&deng[b * 32 + lq], dvq);
}

// ---------------- epilogue (IN-PLACE on d_out): out[row][e'] = sum_d (out[row][d]/den[row]) * value_w[e'][d] ----------------
__global__ __launch_bounds__(256) void vproj_norm(
    const float* __restrict__ deng, const unsigned short* __restrict__ wvb,
    float* __restrict__ out){
  __shared__ unsigned short at[64 * 256];
  __shared__ float dl[64];
  int tid = threadIdx.x, w = tid >> 6, l = tid & 63, h = l >> 4, c = l & 15;
  size_t r0 = (size_t)blockIdx.x * 64;
  if (tid < 64) dl[tid] = 1.f / deng[r0 + tid];
  __syncthreads();
  #pragma unroll
  for (int j = 0; j < 16; ++j){
    int idx = j * 256 + tid;
    int row = idx >> 6, c4 = (idx & 63) * 4;
    f32x4_t v = *(const f32x4_t*)(out + (r0 + row) * 256 + c4);
    float iv = dl[row];
    float v0 = v[0] * iv, v1 = v[1] * iv, v2 = v[2] * iv, v3 = v[3] * iv;
    uint2 p;
    CVTPK(v0, v1, p.x);
    CVTPK(v2, v3, p.y);
    *(uint2*)&at[row * 256 + (c4 ^ ((row & 7) << 3))] = p;
  }
  __syncthreads();
  f32x4_t zero4 = {0.f, 0.f, 0.f, 0.f};
  f32x4_t a2[4][4];
  #pragma unroll
  for (int m = 0; m < 4; ++m)
    #pragma unroll
    for (int nt = 0; nt < 4; ++nt) a2[m][nt] = zero4;
  #pragma unroll
  for (int kk = 0; kk < 8; ++kk){
    bf16x8_t A[4];
    #pragma unroll
    for (int m = 0; m < 4; ++m){
      int row = c + 16 * m;
      A[m] = *(const bf16x8_t*)&at[row * 256 + ((kk * 32 + 8 * h) ^ ((row & 7) << 3))];
    }
    #pragma unroll
    for (int nt = 0; nt < 4; ++nt){
      int ep = 64 * w + 16 * nt + c;
      bf16x8_t Bv = *(const bf16x8_t*)(wvb + (size_t)ep * 256 + kk * 32 + 8 * h);
      #pragma unroll
      for (int m = 0; m < 4; ++m) a2[m][nt] = MFMA16(A[m], Bv, a2[m][nt]);
    }
  }
  #pragma unroll
  for (int m = 0; m < 4; ++m)
    #pragma unroll
    for (int nt = 0; nt < 4; ++nt)
      #pragma unroll
      for (int i = 0; i < 4; ++i){
        size_t row = r0 + 16 * m + 4 * h + i;
        int ep = 64 * w + 16 * nt + c;
        out[row * 256 + ep] = a2[m][nt][i];
      }
}

extern "C" void kernel_launch(void* const* d_in, const int* in_sizes, int n_in,
                              void* d_out, int out_size, void* d_ws, size_t ws_size,
                              hipStream_t stream){
  const float* keys    = (const float*)d_in[0];
  const int*   mask    = (const int*)d_in[1];
  const float* context = (const float*)d_in[2];
  const float* queries = (const float*)d_in[3];
  const float* key_w   = (const float*)d_in[4];
  const float* value_w = (const float*)d_in[5];
  const float* logt    = (const float*)d_in[6];
  const float* cond_w  = (const float*)d_in[7];
  const float* cond_b  = (const float*)d_in[8];
  float* out = (float*)d_out;

  unsigned short* wkt = (unsigned short*)d_ws;           // 65536 bf16
  unsigned short* wvb = wkt + 65536;                     // 65536 bf16
  unsigned short* qs  = wvb + 65536;                     // 16384*256 bf16
  unsigned short* qkp = qs + (size_t)16384 * 256;        // 16384*256 bf16
  float* deng = (float*)(qkp + (size_t)16384 * 256);     // 16384 f32
  int*   nreal = (int*)(deng + 16384);                   // 512 int

  hipLaunchKernelGGL(setup_k,  dim3(384), dim3(256), 0, stream, key_w, value_w, mask, wkt, wvb, nreal);
  hipLaunchKernelGGL(calc_qs,  dim3(256), dim3(256), 0, stream, context, queries, logt, cond_w, cond_b, qs);
  hipLaunchKernelGGL(calc_qkp, dim3(256), dim3(256), 0, stream, qs, wkt, qkp);
  hipLaunchKernelGGL(zero_k,   dim3(4096), dim3(256), 0, stream, (float4*)out, (float4*)deng);
  hipLaunchKernelGGL(attn_part, dim3(1024), dim3(256), 0, stream, keys, nreal, qkp, out, deng);
  hipLaunchKernelGGL(vproj_norm, dim3(256), dim3(256), 0, stream, deng, wvb, out);
}

// Round 13
// 141.138 us; speedup vs baseline: 1.6838x; 1.6838x over previous
//
#include <hip/hip_runtime.h>

typedef short bf16x8_t __attribute__((ext_vector_type(8)));
typedef float f32x4_t  __attribute__((ext_vector_type(4)));
typedef float f32x16_t __attribute__((ext_vector_type(16)));

#define MFMA16(a,b,c) __builtin_amdgcn_mfma_f32_16x16x32_bf16(a,b,c,0,0,0)
#define MFMA32(a,b,c) __builtin_amdgcn_mfma_f32_32x32x16_bf16(a,b,c,0,0,0)
#define CVTPK(lo, hi, dst) asm("v_cvt_pk_bf16_f32 %0, %1, %2" : "=v"(dst) : "v"(lo), "v"(hi))
#define SWAP32(x, y) asm volatile("v_permlane32_swap_b32 %0, %1" : "+v"(x), "+v"(y))

// pack 8 f32 (t-interleaved 32x32 D-layout) into one bf16x8 A/B-fragment (proven in R12)
#define PACKFRAG(V, off, dst) do{                                   \
    unsigned a0_, a1_, b0_, b1_;                                    \
    CVTPK(V[(off)+0], V[(off)+1], a0_);                             \
    CVTPK(V[(off)+2], V[(off)+3], a1_);                             \
    CVTPK(V[(off)+4], V[(off)+5], b0_);                             \
    CVTPK(V[(off)+6], V[(off)+7], b1_);                             \
    SWAP32(a0_, b0_);  SWAP32(a1_, b1_);                            \
    union{ unsigned u[4]; bf16x8_t v; } t_;                         \
    t_.u[0] = a0_; t_.u[1] = a1_; t_.u[2] = b0_; t_.u[3] = b1_;     \
    dst = t_.v;                                                     \
  }while(0)

__device__ __forceinline__ unsigned short f2b(float x){
  unsigned u = __float_as_uint(x);
  u += 0x7fffu + ((u >> 16) & 1u);
  return (unsigned short)(u >> 16);
}

// ---------------- setup: weights -> bf16 (blocks 0..255) + n_real (blocks 256..383) ----------------
__global__ void setup_k(const float* __restrict__ kw, const float* __restrict__ vw,
                        const int* __restrict__ mask,
                        unsigned short* __restrict__ wktb, unsigned short* __restrict__ wvb,
                        int* __restrict__ nreal){
  int bid = blockIdx.x, tid = threadIdx.x;
  if (bid < 256){
    int i = bid * 256 + tid;                       // 0..65535
    int d = i >> 8, e = i & 255;
    wktb[i] = f2b(kw[e * 256 + d]);                // WkT[d][e] (transposed, for calc_qkp)
    wvb[i]  = f2b(vw[i]);                          // value_w as-is (for vproj_norm)
  } else {
    int b = (bid - 256) * 4 + (tid >> 6), l = tid & 63;
    int s_ = 0;
    #pragma unroll
    for (int j = 0; j < 8; ++j) s_ += mask[(size_t)b * 512 + j * 64 + l];
    #pragma unroll
    for (int k = 1; k < 64; k <<= 1) s_ += __shfl_xor(s_, k);
    if (l == 0) nreal[b] = s_ < 1 ? 1 : (s_ > 512 ? 512 : s_);
  }
}

// ---------------- zero out(acc) + denom ----------------
__global__ void zero_k(float4* __restrict__ acc4, float4* __restrict__ den4){
  int i = blockIdx.x * 256 + threadIdx.x;
  float4 z = {0.f, 0.f, 0.f, 0.f};
  acc4[i] = z;                 // grid covers exactly 1048576 float4 (= d_out)
  if (i < 4096) den4[i] = z;
}

// ---------------- qs[b*32+q][e] = (queries[q,e] + context[b]@cond_w[q*256+e] + cond_b)*scale*inv_t ----------------
__global__ __launch_bounds__(256) void calc_qs(
    const float* __restrict__ context, const float* __restrict__ queries,
    const float* __restrict__ logt, const float* __restrict__ condw,
    const float* __restrict__ condb, unsigned short* __restrict__ qs){
  __shared__ float ctx_l[64 * 64];
  int tid = threadIdx.x;
  int q   = blockIdx.x & 31;
  int b0  = (blockIdx.x >> 5) * 64;
  int qd  = q * 256 + tid;
  float4 cw[16];
  #pragma unroll
  for (int j = 0; j < 16; ++j) cw[j] = *(const float4*)(condw + (size_t)qd * 64 + 4 * j);
  float qbias = queries[qd] + condb[qd];
  float sc = 0.0625f * __expf(-logt[q >> 2]);      // scale * inv_temperature
  #pragma unroll
  for (int j = 0; j < 16; ++j){
    int f = j * 256 + tid;
    ctx_l[f] = context[(size_t)b0 * 64 + f];
  }
  __syncthreads();
  for (int b = 0; b < 64; ++b){
    const float4* cl = (const float4*)(ctx_l + b * 64);
    float acc = 0.f;
    #pragma unroll
    for (int j = 0; j < 16; ++j){
      float4 cv = cl[j]; float4 w4 = cw[j];
      acc += cv.x * w4.x + cv.y * w4.y + cv.z * w4.z + cv.w * w4.w;
    }
    qs[((size_t)(b0 + b) * 32 + q) * 256 + tid] = f2b((qbias + acc) * sc);
  }
}

// ---------------- qkp[row][d] = sum_e qs[row][e] * key_w[e][d]   (row = b*32+q) ----------------
__global__ __launch_bounds__(256) void calc_qkp(
    const unsigned short* __restrict__ qs, const unsigned short* __restrict__ wkt,
    unsigned short* __restrict__ qkp){
  __shared__ unsigned short at[64 * 256];
  int tid = threadIdx.x, w = tid >> 6, l = tid & 63, h = l >> 4, c = l & 15;
  size_t r0 = (size_t)blockIdx.x * 64;
  #pragma unroll
  for (int j = 0; j < 8; ++j){
    int f = j * 256 + tid;
    int row = f >> 5, col = (f & 31) * 8;
    bf16x8_t v = *(const bf16x8_t*)(qs + (r0 + row) * 256 + col);
    *(bf16x8_t*)&at[row * 256 + (col ^ ((row & 7) << 3))] = v;
  }
  __syncthreads();
  f32x4_t zero4 = {0.f, 0.f, 0.f, 0.f};
  f32x4_t acc[4][4];
  #pragma unroll
  for (int mt = 0; mt < 4; ++mt)
    #pragma unroll
    for (int nt = 0; nt < 4; ++nt) acc[mt][nt] = zero4;
  #pragma unroll
  for (int kk = 0; kk < 8; ++kk){
    bf16x8_t A[4];
    #pragma unroll
    for (int mt = 0; mt < 4; ++mt){
      int row = c + 16 * mt;
      A[mt] = *(const bf16x8_t*)&at[row * 256 + ((kk * 32 + 8 * h) ^ ((row & 7) << 3))];
    }
    #pragma unroll
    for (int nt = 0; nt < 4; ++nt){
      int d = 64 * w + 16 * nt + c;
      bf16x8_t Bv = *(const bf16x8_t*)(wkt + (size_t)d * 256 + kk * 32 + 8 * h);
      #pragma unroll
      for (int mt = 0; mt < 4; ++mt) acc[mt][nt] = MFMA16(A[mt], Bv, acc[mt][nt]);
    }
  }
  #pragma unroll
  for (int mt = 0; mt < 4; ++mt)
    #pragma unroll
    for (int nt = 0; nt < 4; ++nt)
      #pragma unroll
      for (int i = 0; i < 4; ++i){
        size_t row = r0 + 16 * mt + 4 * h + i;
        int d = 64 * w + 16 * nt + c;
        qkp[row * 256 + d] = f2b(acc[mt][nt][i]);
      }
}

// ---------------- partial attention, FLAT: one block per (batch, 64-row segment) ----------------
// No tile chains: stage 64 keys rows + qkp, ONE barrier, two lane-local 32x32 computations
// (R12's proven MFMA32 layouts), one atomic accumulation. 4096 independent blocks.
__global__ __launch_bounds__(256, 3) void attn_part(
    const float* __restrict__ keys, const int* __restrict__ nreal,
    const unsigned short* __restrict__ qkp,
    float* __restrict__ acc, float* __restrict__ deng){
  __shared__ unsigned short Kd[64 * 256];     // bf16 keys, swizzled (32 KB)
  __shared__ unsigned short qkl[32 * 256];    // qkp rows for this b, swizzled (16 KB)

  int bid = blockIdx.x;
  int b = bid >> 3, seg = bid & 7;
  int n_real = nreal[b];
  int sbase = seg * 64;
  if (sbase >= n_real) return;                 // uniform early-exit, before any barrier

  int tid = threadIdx.x, w = tid >> 6, l = tid & 63;
  int lq = l & 31, hh = l >> 5;

  // stage qkp[b] -> qkl (full-spread swizzle (row&31)<<3)
  #pragma unroll
  for (int j = 0; j < 4; ++j){
    int f = j * 2048 + tid * 8;
    int row = f >> 8, col = f & 255;
    bf16x8_t v = *(const bf16x8_t*)(qkp + ((size_t)b * 32 + row) * 256 + col);
    *(bf16x8_t*)&qkl[row * 256 + (col ^ ((row & 31) << 3))] = v;
  }

  // stage 64 keys rows f32 -> bf16 LDS (16 independent loads/lane in flight)
  const float* kptr = keys + ((size_t)b * 512 + sbase + w) * 256 + 4 * l;
  #pragma unroll
  for (int j = 0; j < 16; ++j){
    float4 kv = *(const float4*)(kptr + j * 1024);
    int row = 4 * j + w;
    uint2 p;
    CVTPK(kv.x, kv.y, p.x);
    CVTPK(kv.z, kv.w, p.y);
    *(uint2*)&Kd[row * 256 + ((4 * l) ^ ((row & 31) << 3))] = p;
  }

  // identity B-fragments for 32x32 transpose (proven in R12)
  bf16x8_t bI0, bI16;
  #pragma unroll
  for (int j = 0; j < 8; ++j){
    bI0[j]  = (j == lq - 8 * hh)      ? (short)0x3F80 : (short)0;
    bI16[j] = (j == lq - 16 - 8 * hh) ? (short)0x3F80 : (short)0;
  }

  float slope0 = exp2f(-2.0f * (float)((lq & 3) + 1));   // head = q&3

  f32x16_t ao0, ao1;
  #pragma unroll
  for (int i = 0; i < 16; ++i){ ao0[i] = 0.f; ao1[i] = 0.f; }
  float dvq = 0.f;

  int sw = lq << 3;
  int qbase = lq * 256;

  __syncthreads();            // the ONLY barrier: Kd + qkl visible

  for (int half = 0; half < 2; ++half){
    int s0 = sbase + 32 * half;
    if (s0 >= n_real) break;                   // uniform
    int rbase = (lq + 32 * half) * 256;

    // ---- logits: S[t][q] = sum_e K[t][e] * qkp[q][e], 16 MFMA32 ----
    f32x16_t Sa, Sb;
    #pragma unroll
    for (int i = 0; i < 16; ++i){ Sa[i] = 0.f; Sb[i] = 0.f; }
    #pragma unroll
    for (int kk = 0; kk < 16; kk += 2){
      bf16x8_t A0 = *(const bf16x8_t*)&Kd[rbase + ((16 * kk + 8 * hh) ^ sw)];
      bf16x8_t B0 = *(const bf16x8_t*)&qkl[qbase + ((16 * kk + 8 * hh) ^ sw)];
      bf16x8_t A1 = *(const bf16x8_t*)&Kd[rbase + ((16 * kk + 16 + 8 * hh) ^ sw)];
      bf16x8_t B1 = *(const bf16x8_t*)&qkl[qbase + ((16 * kk + 16 + 8 * hh) ^ sw)];
      Sa = MFMA32(A0, B0, Sa);
      Sb = MFMA32(A1, B1, Sb);
    }

    // ---- K^T for own e-range via identity MFMA: D0 -> e[64w,64w+32), D1 -> +32 ----
    f32x16_t D0, D1;
    #pragma unroll
    for (int i = 0; i < 16; ++i){ D0[i] = 0.f; D1[i] = 0.f; }
    {
      bf16x8_t T0 = *(const bf16x8_t*)&Kd[rbase + ((16 * (4 * w + 0) + 8 * hh) ^ sw)];
      bf16x8_t T1 = *(const bf16x8_t*)&Kd[rbase + ((16 * (4 * w + 1) + 8 * hh) ^ sw)];
      bf16x8_t T2 = *(const bf16x8_t*)&Kd[rbase + ((16 * (4 * w + 2) + 8 * hh) ^ sw)];
      bf16x8_t T3 = *(const bf16x8_t*)&Kd[rbase + ((16 * (4 * w + 3) + 8 * hh) ^ sw)];
      D0 = MFMA32(T0, bI0, D0);  D0 = MFMA32(T1, bI16, D0);
      D1 = MFMA32(T2, bI0, D1);  D1 = MFMA32(T3, bI16, D1);
    }

    // ---- softmax in-lane (q = lq, 16 t-values, t=(i&3)+8*(i>>2)+4*hh) ----
    float P[16];
    float fb = (float)(n_real - 1 - s0);
    #pragma unroll
    for (int i = 0; i < 16; ++i){
      int t = (i & 3) + 8 * (i >> 2) + 4 * hh;
      float sv = Sa[i] + Sb[i];
      bool valid = (s0 + t) < n_real;
      float pv = valid ? __expf(sv - slope0 * (fb - (float)t)) : 0.f;
      P[i] = pv;
      dvq += pv;
    }

    // ---- P -> PV A-frags; D0/D1 -> PV B-frags (cvt_pk + permlane32_swap) ----
    bf16x8_t Af0, Af1, Bf00, Bf01, Bf10, Bf11;
    PACKFRAG(P,  0, Af0);   PACKFRAG(P,  8, Af1);
    PACKFRAG(D0, 0, Bf00);  PACKFRAG(D0, 8, Bf01);
    PACKFRAG(D1, 0, Bf10);  PACKFRAG(D1, 8, Bf11);

    // ---- PV: out[q][e] += P[q][t] * K[t][e] ----
    ao0 = MFMA32(Af0, Bf00, ao0);
    ao0 = MFMA32(Af1, Bf01, ao0);
    ao1 = MFMA32(Af0, Bf10, ao1);
    ao1 = MFMA32(Af1, Bf11, ao1);
  }

  // ---- accumulate numerators (atomics into d_out) + denominators ----
  #pragma unroll
  for (int i = 0; i < 16; ++i){
    int q = (i & 3) + 8 * (i >> 2) + 4 * hh;
    atomicAdd(&acc[((size_t)b * 32 + q) * 256 + 64 * w + lq], ao0[i]);
    atomicAdd(&acc[((size_t)b * 32 + q) * 256 + 64 * w + 32 + lq], ao1[i]);
  }
  dvq += __shfl_xor(dvq, 32);
  if (w == 0 && hh == 0) atomicAdd(&deng[b * 32 + lq], dvq);
}

// ---------------- epilogue (IN-PLACE on d_out): out[row][e'] = sum_d (out[row][d]/den[row]) * value_w[e'][d] ----------------
__global__ __launch_bounds__(256) void vproj_norm(
    const float* __restrict__ deng, const unsigned short* __restrict__ wvb,
    float* __restrict__ out){
  __shared__ unsigned short at[64 * 256];
  __shared__ float dl[64];
  int tid = threadIdx.x, w = tid >> 6, l = tid & 63, h = l >> 4, c = l & 15;
  size_t r0 = (size_t)blockIdx.x * 64;
  if (tid < 64) dl[tid] = 1.f / deng[r0 + tid];
  __syncthreads();
  #pragma unroll
  for (int j = 0; j < 16; ++j){
    int idx = j * 256 + tid;
    int row = idx >> 6, c4 = (idx & 63) * 4;
    f32x4_t v = *(const f32x4_t*)(out + (r0 + row) * 256 + c4);
    float iv = dl[row];
    float v0 = v[0] * iv, v1 = v[1] * iv, v2 = v[2] * iv, v3 = v[3] * iv;
    uint2 p;
    CVTPK(v0, v1, p.x);
    CVTPK(v2, v3, p.y);
    *(uint2*)&at[row * 256 + (c4 ^ ((row & 7) << 3))] = p;
  }
  __syncthreads();
  f32x4_t zero4 = {0.f, 0.f, 0.f, 0.f};
  f32x4_t a2[4][4];
  #pragma unroll
  for (int m = 0; m < 4; ++m)
    #pragma unroll
    for (int nt = 0; nt < 4; ++nt) a2[m][nt] = zero4;
  #pragma unroll
  for (int kk = 0; kk < 8; ++kk){
    bf16x8_t A[4];
    #pragma unroll
    for (int m = 0; m < 4; ++m){
      int row = c + 16 * m;
      A[m] = *(const bf16x8_t*)&at[row * 256 + ((kk * 32 + 8 * h) ^ ((row & 7) << 3))];
    }
    #pragma unroll
    for (int nt = 0; nt < 4; ++nt){
      int ep = 64 * w + 16 * nt + c;
      bf16x8_t Bv = *(const bf16x8_t*)(wvb + (size_t)ep * 256 + kk * 32 + 8 * h);
      #pragma unroll
      for (int m = 0; m < 4; ++m) a2[m][nt] = MFMA16(A[m], Bv, a2[m][nt]);
    }
  }
  #pragma unroll
  for (int m = 0; m < 4; ++m)
    #pragma unroll
    for (int nt = 0; nt < 4; ++nt)
      #pragma unroll
      for (int i = 0; i < 4; ++i){
        size_t row = r0 + 16 * m + 4 * h + i;
        int ep = 64 * w + 16 * nt + c;
        out[row * 256 + ep] = a2[m][nt][i];
      }
}

extern "C" void kernel_launch(void* const* d_in, const int* in_sizes, int n_in,
                              void* d_out, int out_size, void* d_ws, size_t ws_size,
                              hipStream_t stream){
  const float* keys    = (const float*)d_in[0];
  const int*   mask    = (const int*)d_in[1];
  const float* context = (const float*)d_in[2];
  const float* queries = (const float*)d_in[3];
  const float* key_w   = (const float*)d_in[4];
  const float* value_w = (const float*)d_in[5];
  const float* logt    = (const float*)d_in[6];
  const float* cond_w  = (const float*)d_in[7];
  const float* cond_b  = (const float*)d_in[8];
  float* out = (float*)d_out;

  unsigned short* wkt = (unsigned short*)d_ws;           // 65536 bf16
  unsigned short* wvb = wkt + 65536;                     // 65536 bf16
  unsigned short* qs  = wvb + 65536;                     // 16384*256 bf16
  unsigned short* qkp = qs + (size_t)16384 * 256;        // 16384*256 bf16
  float* deng = (float*)(qkp + (size_t)16384 * 256);     // 16384 f32
  int*   nreal = (int*)(deng + 16384);                   // 512 int

  hipLaunchKernelGGL(setup_k,  dim3(384), dim3(256), 0, stream, key_w, value_w, mask, wkt, wvb, nreal);
  hipLaunchKernelGGL(calc_qs,  dim3(256), dim3(256), 0, stream, context, queries, logt, cond_w, cond_b, qs);
  hipLaunchKernelGGL(calc_qkp, dim3(256), dim3(256), 0, stream, qs, wkt, qkp);
  hipLaunchKernelGGL(zero_k,   dim3(4096), dim3(256), 0, stream, (float4*)out, (float4*)deng);
  hipLaunchKernelGGL(attn_part, dim3(4096), dim3(256), 0, stream, keys, nreal, qkp, out, deng);
  hipLaunchKernelGGL(vproj_norm, dim3(256), dim3(256), 0, stream, deng, wvb, out);
}

// Round 14
// 133.790 us; speedup vs baseline: 1.7763x; 1.0549x over previous
//
#include <hip/hip_runtime.h>

typedef short bf16x8_t __attribute__((ext_vector_type(8)));
typedef float f32x4_t  __attribute__((ext_vector_type(4)));

#define MFMA16(a,b,c) __builtin_amdgcn_mfma_f32_16x16x32_bf16(a,b,c,0,0,0)

__device__ __forceinline__ unsigned short f2b(float x){
  unsigned u = __float_as_uint(x);
  u += 0x7fffu + ((u >> 16) & 1u);
  return (unsigned short)(u >> 16);
}

__device__ __forceinline__ void bar_lgkm(){
  asm volatile("s_waitcnt lgkmcnt(0)" ::: "memory");
  __builtin_amdgcn_s_barrier();
  __builtin_amdgcn_sched_barrier(0);
}

// ---------------- prep: WkT[d][e] = bf16(key_w[e][d]) (transposed);  Wvb = bf16(value_w) as-is ----------------
__global__ void prep_w(const float* __restrict__ kw, const float* __restrict__ vw,
                       unsigned short* __restrict__ wktb, unsigned short* __restrict__ wvb){
  int i = blockIdx.x * 256 + threadIdx.x;          // 0..65535
  int d = i >> 8, e = i & 255;
  wktb[i] = f2b(kw[e * 256 + d]);
  wvb[i]  = f2b(vw[i]);
}

// ---------------- n_real[b] = clamp(sum mask row) ----------------
__global__ void nreal_k(const int* __restrict__ mask, int* __restrict__ nreal){
  int b = blockIdx.x, l = threadIdx.x;
  int s_ = 0;
  #pragma unroll
  for (int j = 0; j < 8; ++j) s_ += mask[(size_t)b * 512 + j * 64 + l];
  #pragma unroll
  for (int k = 1; k < 64; k <<= 1) s_ += __shfl_xor(s_, k);
  if (l == 0) nreal[b] = s_ < 1 ? 1 : (s_ > 512 ? 512 : s_);
}

// ---------------- zero out(acc) + denom ----------------
__global__ void zero_k(float4* __restrict__ acc4, float4* __restrict__ den4){
  int i = blockIdx.x * 256 + threadIdx.x;
  float4 z = {0.f, 0.f, 0.f, 0.f};
  acc4[i] = z;                 // grid covers exactly 1048576 float4 (= d_out)
  if (i < 4096) den4[i] = z;
}

// ---------------- qs[b*32+q][e] = (queries[q,e] + context[b]@cond_w[q*256+e] + cond_b)*scale*inv_t ----------------
__global__ __launch_bounds__(256) void calc_qs(
    const float* __restrict__ context, const float* __restrict__ queries,
    const float* __restrict__ logt, const float* __restrict__ condw,
    const float* __restrict__ condb, unsigned short* __restrict__ qs){
  __shared__ float ctx_l[64 * 64];
  int tid = threadIdx.x;
  int q   = blockIdx.x & 31;
  int b0  = (blockIdx.x >> 5) * 64;
  int qd  = q * 256 + tid;
  float4 cw[16];
  #pragma unroll
  for (int j = 0; j < 16; ++j) cw[j] = *(const float4*)(condw + (size_t)qd * 64 + 4 * j);
  float qbias = queries[qd] + condb[qd];
  float sc = 0.0625f * __expf(-logt[q >> 2]);      // scale * inv_temperature
  #pragma unroll
  for (int j = 0; j < 16; ++j){
    int f = j * 256 + tid;
    ctx_l[f] = context[(size_t)b0 * 64 + f];
  }
  __syncthreads();
  for (int b = 0; b < 64; ++b){
    const float4* cl = (const float4*)(ctx_l + b * 64);
    float acc = 0.f;
    #pragma unroll
    for (int j = 0; j < 16; ++j){
      float4 cv = cl[j]; float4 w4 = cw[j];
      acc += cv.x * w4.x + cv.y * w4.y + cv.z * w4.z + cv.w * w4.w;
    }
    qs[((size_t)(b0 + b) * 32 + q) * 256 + tid] = f2b((qbias + acc) * sc);
  }
}

// ---------------- qkp[row][d] = sum_e qs[row][e] * key_w[e][d]   (row = b*32+q) ----------------
__global__ __launch_bounds__(256) void calc_qkp(
    const unsigned short* __restrict__ qs, const unsigned short* __restrict__ wkt,
    unsigned short* __restrict__ qkp){
  __shared__ unsigned short at[64 * 256];
  int tid = threadIdx.x, w = tid >> 6, l = tid & 63, h = l >> 4, c = l & 15;
  size_t r0 = (size_t)blockIdx.x * 64;
  #pragma unroll
  for (int j = 0; j < 8; ++j){
    int f = j * 256 + tid;
    int row = f >> 5, col = (f & 31) * 8;
    bf16x8_t v = *(const bf16x8_t*)(qs + (r0 + row) * 256 + col);
    *(bf16x8_t*)&at[row * 256 + (col ^ ((row & 7) << 3))] = v;
  }
  __syncthreads();
  f32x4_t zero4 = {0.f, 0.f, 0.f, 0.f};
  f32x4_t acc[4][4];
  #pragma unroll
  for (int mt = 0; mt < 4; ++mt)
    #pragma unroll
    for (int nt = 0; nt < 4; ++nt) acc[mt][nt] = zero4;
  #pragma unroll
  for (int kk = 0; kk < 8; ++kk){
    bf16x8_t A[4];
    #pragma unroll
    for (int mt = 0; mt < 4; ++mt){
      int row = c + 16 * mt;
      A[mt] = *(const bf16x8_t*)&at[row * 256 + ((kk * 32 + 8 * h) ^ ((row & 7) << 3))];
    }
    #pragma unroll
    for (int nt = 0; nt < 4; ++nt){
      int d = 64 * w + 16 * nt + c;
      bf16x8_t Bv = *(const bf16x8_t*)(wkt + (size_t)d * 256 + kk * 32 + 8 * h);
      #pragma unroll
      for (int mt = 0; mt < 4; ++mt) acc[mt][nt] = MFMA16(A[mt], Bv, acc[mt][nt]);
    }
  }
  #pragma unroll
  for (int mt = 0; mt < 4; ++mt)
    #pragma unroll
    for (int nt = 0; nt < 4; ++nt)
      #pragma unroll
      for (int i = 0; i < 4; ++i){
        size_t row = r0 + 16 * mt + 4 * h + i;
        int d = 64 * w + 16 * nt + c;
        qkp[row * 256 + d] = f2b(acc[mt][nt][i]);
      }
}

// ---------------- partial attention over RAW keys: one block per (batch, 256-pos chunk) ----------------
// acc[q,e] += sum_s P[q,s] * keys[s,e] (atomics into d_out); Wv applied in epilogue GEMM.
// EXACT R6 inner structure. Single change: pair-preserving XCD swizzle so both chunks of a batch
// (same atomic target lines, same qkp) run on the SAME XCD; each XCD owns 64 contiguous b's.
__global__ __launch_bounds__(256, 3) void attn_part(
    const float* __restrict__ keys, const int* __restrict__ nreal,
    const unsigned short* __restrict__ qkp,
    float* __restrict__ acc, float* __restrict__ deng){
  __shared__ unsigned short K[32 * 256];   // bf16 keys, swizzled, 16 KB
  __shared__ unsigned short vT[256 * 32];  // K^T [e][t], swizzled, 16 KB
  __shared__ unsigned short Pl[32 * 32];   // P [q][t] bf16, 2 KB
  __shared__ float denl[32];

  // XCD pair swizzle: hw bid -> logical lbid; 1024 = 8 XCD chunks x 128 (bijective).
  // Round-robin hw dispatch => chunk c = bid&7 stays on one XCD; consecutive logical
  // blocks (pairs of the same b) are consecutive slots within a chunk.
  int lbid = (blockIdx.x & 7) * 128 + (blockIdx.x >> 3);
  int b = lbid >> 1, ch = lbid & 1;
  int n_real = nreal[b];
  int sbase = ch * 256;
  if (sbase >= n_real) return;                 // uniform early-exit, before any barrier

  int tid = threadIdx.x, w = tid >> 6, l = tid & 63, h = l >> 4, c = l & 15;
  int mt = w & 1, qt = w >> 1;
  if (tid < 32) denl[tid] = 0.f;

  // identity B-fragments for MFMA-transpose (exact for bf16 inputs)
  bf16x8_t bIe, bIo;
  #pragma unroll
  for (int j = 0; j < 8; ++j){
    bIe[j] = (h == (c >> 3)     && j == (c & 7)) ? (short)0x3F80 : (short)0;
    bIo[j] = (h == 2 + (c >> 3) && j == (c & 7)) ? (short)0x3F80 : (short)0;
  }

  // stage tile 0 into registers (8 x dwordx4 per lane; rows t = 4j + w, cols 4l..4l+3)
  const float* kptr = keys + ((size_t)b * 512 + sbase + w) * 256 + 4 * l;
  float4 R[8];
  #pragma unroll
  for (int j = 0; j < 8; ++j) R[j] = *(const float4*)(kptr + j * 1024);

  // this wave's qkp fragments (B-operand of logits MFMA)
  bf16x8_t qf[8];
  #pragma unroll
  for (int kk = 0; kk < 8; ++kk)
    qf[kk] = *(const bf16x8_t*)(qkp + ((size_t)b * 32 + 16 * qt + c) * 256 + kk * 32 + 8 * h);

  float slope0 = exp2f(-2.0f * (float)((c & 3) + 1));   // head = q&3

  f32x4_t zero4 = {0.f, 0.f, 0.f, 0.f};
  f32x4_t ao[2][4];
  #pragma unroll
  for (int q2 = 0; q2 < 2; ++q2)
    #pragma unroll
    for (int nt = 0; nt < 4; ++nt) ao[q2][nt] = zero4;

  int tend = (n_real - sbase + 31) >> 5; if (tend > 8) tend = 8;

  for (int it = 0; it < tend; ++it){
    int s0 = sbase + it * 32;
    // ---- convert R -> K (bf16, swizzled); interleave issue of next tile's loads ----
    const float* knext = kptr + (size_t)(it + 1) * (32 * 256);
    #pragma unroll
    for (int j = 0; j < 8; ++j){
      int row = 4 * j + w;
      int d4 = 4 * l;
      float4 kv = R[j];
      if (it + 1 < tend) R[j] = *(const float4*)(knext + j * 1024);
      uint2 p;
      p.x = (unsigned)f2b(kv.x) | ((unsigned)f2b(kv.y) << 16);
      p.y = (unsigned)f2b(kv.z) | ((unsigned)f2b(kv.w) << 16);
      *(uint2*)&K[row * 256 + (d4 ^ ((row & 7) << 3))] = p;
    }
    bar_lgkm();                          // BAR1: K visible; staging loads stay in flight

    // ---- logits + K^T (via identity MFMA) ----
    f32x4_t as_ = zero4;
    f32x4_t avT[2][4];
    #pragma unroll
    for (int kk = 0; kk < 8; ++kk){
      int colk = kk * 32 + 8 * h;
      bf16x8_t A0 = *(const bf16x8_t*)&K[c * 256 + (colk ^ ((c & 7) << 3))];
      bf16x8_t A1 = *(const bf16x8_t*)&K[(c + 16) * 256 + (colk ^ ((c & 7) << 3))];
      as_ = MFMA16(mt ? A1 : A0, qf[kk], as_);
      if (kk == 2 * w){
        avT[0][0] = MFMA16(A0, bIe, zero4);  avT[0][1] = MFMA16(A0, bIo, zero4);
        avT[1][0] = MFMA16(A1, bIe, zero4);  avT[1][1] = MFMA16(A1, bIo, zero4);
      }
      if (kk == 2 * w + 1){
        avT[0][2] = MFMA16(A0, bIe, zero4);  avT[0][3] = MFMA16(A0, bIo, zero4);
        avT[1][2] = MFMA16(A1, bIe, zero4);  avT[1][3] = MFMA16(A1, bIo, zero4);
      }
    }
    // vT[e][t] <- K^T (each wave owns e-range 64w..64w+63)
    #pragma unroll
    for (int m = 0; m < 2; ++m)
      #pragma unroll
      for (int nt = 0; nt < 4; ++nt){
        int e = 64 * w + 16 * nt + c;
        int t0 = 16 * m + 4 * h;
        uint2 p;
        p.x = (unsigned)f2b(avT[m][nt][0]) | ((unsigned)f2b(avT[m][nt][1]) << 16);
        p.y = (unsigned)f2b(avT[m][nt][2]) | ((unsigned)f2b(avT[m][nt][3]) << 16);
        *(uint2*)&vT[e * 32 + (t0 ^ ((e & 1) << 3))] = p;
      }

    // ---- softmax (fixed-max): P = exp(logit - slope*games_ago), masked -> 0 ----
    {
      float e_[4]; float qs_ = 0.f;
      #pragma unroll
      for (int i = 0; i < 4; ++i){
        int s = s0 + 16 * mt + 4 * h + i;
        float ga = (float)(n_real - 1 - s);
        bool valid = (s < n_real);
        float v = valid ? __expf(as_[i] - slope0 * ga) : 0.f;
        e_[i] = v; qs_ += v;
      }
      float r = qs_ + __shfl_xor(qs_, 16); r += __shfl_xor(r, 32);
      if (l < 16) atomicAdd(&denl[16 * qt + c], r);
      int q = 16 * qt + c;
      int t0 = 16 * mt + 4 * h;
      uint2 p;
      p.x = (unsigned)f2b(e_[0]) | ((unsigned)f2b(e_[1]) << 16);
      p.y = (unsigned)f2b(e_[2]) | ((unsigned)f2b(e_[3]) << 16);
      *(uint2*)&Pl[q * 32 + (t0 ^ ((q & 1) << 3))] = p;
    }
    bar_lgkm();                          // BAR2: vT/Pl visible; K consumed

    // ---- PV over raw keys: ao[q][e] += P[q][t] * K[t][e] ----
    {
      bf16x8_t Ap0 = *(const bf16x8_t*)&Pl[c * 32 + ((8 * h) ^ ((c & 1) << 3))];
      bf16x8_t Ap1 = *(const bf16x8_t*)&Pl[(16 + c) * 32 + ((8 * h) ^ ((c & 1) << 3))];
      #pragma unroll
      for (int nt = 0; nt < 4; ++nt){
        int e = 64 * w + 16 * nt + c;
        bf16x8_t Bv = *(const bf16x8_t*)&vT[e * 32 + ((8 * h) ^ ((e & 1) << 3))];
        ao[0][nt] = MFMA16(Ap0, Bv, ao[0][nt]);
        ao[1][nt] = MFMA16(Ap1, Bv, ao[1][nt]);
      }
    }
  }

  // ---- accumulate partial numerators / denominators (XCD-local lines after swizzle) ----
  #pragma unroll
  for (int q2 = 0; q2 < 2; ++q2)
    #pragma unroll
    for (int nt = 0; nt < 4; ++nt){
      int e = 64 * w + 16 * nt + c;
      #pragma unroll
      for (int i = 0; i < 4; ++i){
        int q = 16 * q2 + 4 * h + i;
        atomicAdd(&acc[((size_t)b * 32 + q) * 256 + e], ao[q2][nt][i]);
      }
    }
  if (tid < 32) atomicAdd(&deng[b * 32 + tid], denl[tid]);
}

// ---------------- epilogue (IN-PLACE on d_out): out[row][e'] = sum_d (out[row][d]/den[row]) * value_w[e'][d] ----------------
__global__ __launch_bounds__(256) void vproj_norm(
    const float* __restrict__ deng, const unsigned short* __restrict__ wvb,
    float* __restrict__ out){
  __shared__ unsigned short at[64 * 256];
  __shared__ float dl[64];
  int tid = threadIdx.x, w = tid >> 6, l = tid & 63, h = l >> 4, c = l & 15;
  size_t r0 = (size_t)blockIdx.x * 64;
  if (tid < 64) dl[tid] = 1.f / deng[r0 + tid];
  __syncthreads();
  #pragma unroll
  for (int j = 0; j < 16; ++j){
    int idx = j * 256 + tid;
    int row = idx >> 6, c4 = (idx & 63) * 4;
    f32x4_t v = *(const f32x4_t*)(out + (r0 + row) * 256 + c4);
    float iv = dl[row];
    uint2 p;
    p.x = (unsigned)f2b(v[0] * iv) | ((unsigned)f2b(v[1] * iv) << 16);
    p.y = (unsigned)f2b(v[2] * iv) | ((unsigned)f2b(v[3] * iv) << 16);
    *(uint2*)&at[row * 256 + (c4 ^ ((row & 7) << 3))] = p;
  }
  __syncthreads();
  f32x4_t zero4 = {0.f, 0.f, 0.f, 0.f};
  f32x4_t a2[4][4];
  #pragma unroll
  for (int m = 0; m < 4; ++m)
    #pragma unroll
    for (int nt = 0; nt < 4; ++nt) a2[m][nt] = zero4;
  #pragma unroll
  for (int kk = 0; kk < 8; ++kk){
    bf16x8_t A[4];
    #pragma unroll
    for (int m = 0; m < 4; ++m){
      int row = c + 16 * m;
      A[m] = *(const bf16x8_t*)&at[row * 256 + ((kk * 32 + 8 * h) ^ ((row & 7) << 3))];
    }
    #pragma unroll
    for (int nt = 0; nt < 4; ++nt){
      int ep = 64 * w + 16 * nt + c;
      bf16x8_t Bv = *(const bf16x8_t*)(wvb + (size_t)ep * 256 + kk * 32 + 8 * h);
      #pragma unroll
      for (int m = 0; m < 4; ++m) a2[m][nt] = MFMA16(A[m], Bv, a2[m][nt]);
    }
  }
  #pragma unroll
  for (int m = 0; m < 4; ++m)
    #pragma unroll
    for (int nt = 0; nt < 4; ++nt)
      #pragma unroll
      for (int i = 0; i < 4; ++i){
        size_t row = r0 + 16 * m + 4 * h + i;
        int ep = 64 * w + 16 * nt + c;
        out[row * 256 + ep] = a2[m][nt][i];
      }
}

extern "C" void kernel_launch(void* const* d_in, const int* in_sizes, int n_in,
                              void* d_out, int out_size, void* d_ws, size_t ws_size,
                              hipStream_t stream){
  const float* keys    = (const float*)d_in[0];
  const int*   mask    = (const int*)d_in[1];
  const float* context = (const float*)d_in[2];
  const float* queries = (const float*)d_in[3];
  const float* key_w   = (const float*)d_in[4];
  const float* value_w = (const float*)d_in[5];
  const float* logt    = (const float*)d_in[6];
  const float* cond_w  = (const float*)d_in[7];
  const float* cond_b  = (const float*)d_in[8];
  float* out = (float*)d_out;

  unsigned short* wkt = (unsigned short*)d_ws;           // 65536 bf16
  unsigned short* wvb = wkt + 65536;                     // 65536 bf16
  unsigned short* qs  = wvb + 65536;                     // 16384*256 bf16
  unsigned short* qkp = qs + (size_t)16384 * 256;        // 16384*256 bf16
  float* deng = (float*)(qkp + (size_t)16384 * 256);     // 16384 f32
  int*   nreal = (int*)(deng + 16384);                   // 512 int

  hipLaunchKernelGGL(prep_w,   dim3(256), dim3(256), 0, stream, key_w, value_w, wkt, wvb);
  hipLaunchKernelGGL(nreal_k,  dim3(512), dim3(64),  0, stream, mask, nreal);
  hipLaunchKernelGGL(calc_qs,  dim3(256), dim3(256), 0, stream, context, queries, logt, cond_w, cond_b, qs);
  hipLaunchKernelGGL(calc_qkp, dim3(256), dim3(256), 0, stream, qs, wkt, qkp);
  hipLaunchKernelGGL(zero_k,   dim3(4096), dim3(256), 0, stream, (float4*)out, (float4*)deng);
  hipLaunchKernelGGL(attn_part, dim3(1024), dim3(256), 0, stream, keys, nreal, qkp, out, deng);
  hipLaunchKernelGGL(vproj_norm, dim3(256), dim3(256), 0, stream, deng, wvb, out);
}

// Round 15
// 115.749 us; speedup vs baseline: 2.0531x; 1.1559x over previous
//
#include <hip/hip_runtime.h>

typedef short bf16x8_t __attribute__((ext_vector_type(8)));
typedef float f32x4_t  __attribute__((ext_vector_type(4)));

#define MFMA16(a,b,c) __builtin_amdgcn_mfma_f32_16x16x32_bf16(a,b,c,0,0,0)

__device__ __forceinline__ unsigned short f2b(float x){
  unsigned u = __float_as_uint(x);
  u += 0x7fffu + ((u >> 16) & 1u);
  return (unsigned short)(u >> 16);
}

__device__ __forceinline__ void bar_lgkm(){
  asm volatile("s_waitcnt lgkmcnt(0)" ::: "memory");
  __builtin_amdgcn_s_barrier();
  __builtin_amdgcn_sched_barrier(0);
}

// ---------------- unified setup: zero out+denom (0..4095) | weights (4096..4351) | n_real (4352..4479) ----------------
__global__ void setup_k(const float* __restrict__ kw, const float* __restrict__ vw,
                        const int* __restrict__ mask,
                        float4* __restrict__ acc4, float4* __restrict__ den4,
                        unsigned short* __restrict__ wktb, unsigned short* __restrict__ wvb,
                        int* __restrict__ nreal){
  int bid = blockIdx.x, tid = threadIdx.x;
  if (bid < 4096){
    int i = bid * 256 + tid;                       // 0..1048575 float4 (= d_out)
    float4 z = {0.f, 0.f, 0.f, 0.f};
    acc4[i] = z;
    if (i < 4096) den4[i] = z;
  } else if (bid < 4352){
    int i = (bid - 4096) * 256 + tid;              // 0..65535
    int d = i >> 8, e = i & 255;
    wktb[i] = f2b(kw[e * 256 + d]);                // WkT[d][e] (transposed, for calc_qkp)
    wvb[i]  = f2b(vw[i]);                          // value_w as-is (for vproj_norm)
  } else {
    int b = (bid - 4352) * 4 + (tid >> 6), l = tid & 63;
    int s_ = 0;
    #pragma unroll
    for (int j = 0; j < 8; ++j) s_ += mask[(size_t)b * 512 + j * 64 + l];
    #pragma unroll
    for (int k = 1; k < 64; k <<= 1) s_ += __shfl_xor(s_, k);
    if (l == 0) nreal[b] = s_ < 1 ? 1 : (s_ > 512 ? 512 : s_);
  }
}

// ---------------- qs[b*32+q][e] = (queries[q,e] + context[b]@cond_w[q*256+e] + cond_b)*scale*inv_t ----------------
// 2048 blocks: (b-group of 8) x (q). cond_w rows are L2/L3-hot across b-groups.
__global__ __launch_bounds__(256) void calc_qs(
    const float* __restrict__ context, const float* __restrict__ queries,
    const float* __restrict__ logt, const float* __restrict__ condw,
    const float* __restrict__ condb, unsigned short* __restrict__ qs){
  __shared__ float ctx_l[8 * 64];
  int tid = threadIdx.x;
  int q   = blockIdx.x & 31;
  int b0  = (blockIdx.x >> 5) * 8;
  int qd  = q * 256 + tid;
  float4 cw[16];
  #pragma unroll
  for (int j = 0; j < 16; ++j) cw[j] = *(const float4*)(condw + (size_t)qd * 64 + 4 * j);
  float qbias = queries[qd] + condb[qd];
  float sc = 0.0625f * __expf(-logt[q >> 2]);      // scale * inv_temperature
  ctx_l[tid]       = context[(size_t)b0 * 64 + tid];
  ctx_l[tid + 256] = context[(size_t)b0 * 64 + tid + 256];
  __syncthreads();
  #pragma unroll
  for (int b = 0; b < 8; ++b){
    const float4* cl = (const float4*)(ctx_l + b * 64);
    float acc = 0.f;
    #pragma unroll
    for (int j = 0; j < 16; ++j){
      float4 cv = cl[j]; float4 w4 = cw[j];
      acc += cv.x * w4.x + cv.y * w4.y + cv.z * w4.z + cv.w * w4.w;
    }
    qs[((size_t)(b0 + b) * 32 + q) * 256 + tid] = f2b((qbias + acc) * sc);
  }
}

// ---------------- qkp[row][d] = sum_e qs[row][e] * key_w[e][d]   (row = b*32+q) ----------------
__global__ __launch_bounds__(256) void calc_qkp(
    const unsigned short* __restrict__ qs, const unsigned short* __restrict__ wkt,
    unsigned short* __restrict__ qkp){
  __shared__ unsigned short at[64 * 256];
  int tid = threadIdx.x, w = tid >> 6, l = tid & 63, h = l >> 4, c = l & 15;
  size_t r0 = (size_t)blockIdx.x * 64;
  #pragma unroll
  for (int j = 0; j < 8; ++j){
    int f = j * 256 + tid;
    int row = f >> 5, col = (f & 31) * 8;
    bf16x8_t v = *(const bf16x8_t*)(qs + (r0 + row) * 256 + col);
    *(bf16x8_t*)&at[row * 256 + (col ^ ((row & 7) << 3))] = v;
  }
  __syncthreads();
  f32x4_t zero4 = {0.f, 0.f, 0.f, 0.f};
  f32x4_t acc[4][4];
  #pragma unroll
  for (int mt = 0; mt < 4; ++mt)
    #pragma unroll
    for (int nt = 0; nt < 4; ++nt) acc[mt][nt] = zero4;
  #pragma unroll
  for (int kk = 0; kk < 8; ++kk){
    bf16x8_t A[4];
    #pragma unroll
    for (int mt = 0; mt < 4; ++mt){
      int row = c + 16 * mt;
      A[mt] = *(const bf16x8_t*)&at[row * 256 + ((kk * 32 + 8 * h) ^ ((row & 7) << 3))];
    }
    #pragma unroll
    for (int nt = 0; nt < 4; ++nt){
      int d = 64 * w + 16 * nt + c;
      bf16x8_t Bv = *(const bf16x8_t*)(wkt + (size_t)d * 256 + kk * 32 + 8 * h);
      #pragma unroll
      for (int mt = 0; mt < 4; ++mt) acc[mt][nt] = MFMA16(A[mt], Bv, acc[mt][nt]);
    }
  }
  #pragma unroll
  for (int mt = 0; mt < 4; ++mt)
    #pragma unroll
    for (int nt = 0; nt < 4; ++nt)
      #pragma unroll
      for (int i = 0; i < 4; ++i){
        size_t row = r0 + 16 * mt + 4 * h + i;
        int d = 64 * w + 16 * nt + c;
        qkp[row * 256 + d] = f2b(acc[mt][nt][i]);
      }
}

// ---------------- partial attention over RAW keys: one block per (batch, 256-pos chunk) ----------------
// R14 base (XCD pair-swizzle kept). Deltas: streamed vT writes (peak VGPR < 128) +
// __launch_bounds__(256,4) -> 4 waves/SIMD -> 4 blocks/CU (was VGPR-capped at 3).
__global__ __launch_bounds__(256, 4) void attn_part(
    const float* __restrict__ keys, const int* __restrict__ nreal,
    const unsigned short* __restrict__ qkp,
    float* __restrict__ acc, float* __restrict__ deng){
  __shared__ unsigned short K[32 * 256];   // bf16 keys, swizzled, 16 KB
  __shared__ unsigned short vT[256 * 32];  // K^T [e][t], swizzled, 16 KB
  __shared__ unsigned short Pl[32 * 32];   // P [q][t] bf16, 2 KB
  __shared__ float denl[32];

  // XCD pair swizzle: both chunks of a batch stay on one XCD (R14 win)
  int lbid = (blockIdx.x & 7) * 128 + (blockIdx.x >> 3);
  int b = lbid >> 1, ch = lbid & 1;
  int n_real = nreal[b];
  int sbase = ch * 256;
  if (sbase >= n_real) return;                 // uniform early-exit, before any barrier

  int tid = threadIdx.x, w = tid >> 6, l = tid & 63, h = l >> 4, c = l & 15;
  int mt = w & 1, qt = w >> 1;
  if (tid < 32) denl[tid] = 0.f;

  // identity B-fragments for MFMA-transpose (exact for bf16 inputs)
  bf16x8_t bIe, bIo;
  #pragma unroll
  for (int j = 0; j < 8; ++j){
    bIe[j] = (h == (c >> 3)     && j == (c & 7)) ? (short)0x3F80 : (short)0;
    bIo[j] = (h == 2 + (c >> 3) && j == (c & 7)) ? (short)0x3F80 : (short)0;
  }

  // stage tile 0 into registers (8 x dwordx4 per lane; rows t = 4j + w, cols 4l..4l+3)
  const float* kptr = keys + ((size_t)b * 512 + sbase + w) * 256 + 4 * l;
  float4 R[8];
  #pragma unroll
  for (int j = 0; j < 8; ++j) R[j] = *(const float4*)(kptr + j * 1024);

  // this wave's qkp fragments (B-operand of logits MFMA)
  bf16x8_t qf[8];
  #pragma unroll
  for (int kk = 0; kk < 8; ++kk)
    qf[kk] = *(const bf16x8_t*)(qkp + ((size_t)b * 32 + 16 * qt + c) * 256 + kk * 32 + 8 * h);

  float slope0 = exp2f(-2.0f * (float)((c & 3) + 1));   // head = q&3

  f32x4_t zero4 = {0.f, 0.f, 0.f, 0.f};
  f32x4_t ao[2][4];
  #pragma unroll
  for (int q2 = 0; q2 < 2; ++q2)
    #pragma unroll
    for (int nt = 0; nt < 4; ++nt) ao[q2][nt] = zero4;

  int tend = (n_real - sbase + 31) >> 5; if (tend > 8) tend = 8;

  for (int it = 0; it < tend; ++it){
    int s0 = sbase + it * 32;
    // ---- convert R -> K (bf16, swizzled); interleave issue of next tile's loads ----
    const float* knext = kptr + (size_t)(it + 1) * (32 * 256);
    #pragma unroll
    for (int j = 0; j < 8; ++j){
      int row = 4 * j + w;
      int d4 = 4 * l;
      float4 kv = R[j];
      if (it + 1 < tend) R[j] = *(const float4*)(knext + j * 1024);
      uint2 p;
      p.x = (unsigned)f2b(kv.x) | ((unsigned)f2b(kv.y) << 16);
      p.y = (unsigned)f2b(kv.z) | ((unsigned)f2b(kv.w) << 16);
      *(uint2*)&K[row * 256 + (d4 ^ ((row & 7) << 3))] = p;
    }
    bar_lgkm();                          // BAR1: K visible; staging loads stay in flight

    // ---- logits + K^T (identity MFMA), K^T streamed straight to vT (low reg pressure) ----
    f32x4_t as_ = zero4;
    #pragma unroll
    for (int kk = 0; kk < 8; ++kk){
      int colk = kk * 32 + 8 * h;
      bf16x8_t A0 = *(const bf16x8_t*)&K[c * 256 + (colk ^ ((c & 7) << 3))];
      bf16x8_t A1 = *(const bf16x8_t*)&K[(c + 16) * 256 + (colk ^ ((c & 7) << 3))];
      as_ = MFMA16(mt ? A1 : A0, qf[kk], as_);
      if ((kk >> 1) == w){               // this wave's e-range: cols 64w..64w+63 (kk = 2w, 2w+1)
        int ntb = (kk & 1) << 1;
        f32x4_t tA = MFMA16(A0, bIe, zero4);   // m=0, nt=ntb
        f32x4_t tB = MFMA16(A0, bIo, zero4);   // m=0, nt=ntb+1
        f32x4_t tC = MFMA16(A1, bIe, zero4);   // m=1, nt=ntb
        f32x4_t tD = MFMA16(A1, bIo, zero4);   // m=1, nt=ntb+1
        int e0 = 64 * w + 16 * ntb + c;
        int e1 = e0 + 16;
        uint2 p;
        p.x = (unsigned)f2b(tA[0]) | ((unsigned)f2b(tA[1]) << 16);
        p.y = (unsigned)f2b(tA[2]) | ((unsigned)f2b(tA[3]) << 16);
        *(uint2*)&vT[e0 * 32 + ((4 * h) ^ ((e0 & 1) << 3))] = p;
        p.x = (unsigned)f2b(tB[0]) | ((unsigned)f2b(tB[1]) << 16);
        p.y = (unsigned)f2b(tB[2]) | ((unsigned)f2b(tB[3]) << 16);
        *(uint2*)&vT[e1 * 32 + ((4 * h) ^ ((e1 & 1) << 3))] = p;
        p.x = (unsigned)f2b(tC[0]) | ((unsigned)f2b(tC[1]) << 16);
        p.y = (unsigned)f2b(tC[2]) | ((unsigned)f2b(tC[3]) << 16);
        *(uint2*)&vT[e0 * 32 + ((16 + 4 * h) ^ ((e0 & 1) << 3))] = p;
        p.x = (unsigned)f2b(tD[0]) | ((unsigned)f2b(tD[1]) << 16);
        p.y = (unsigned)f2b(tD[2]) | ((unsigned)f2b(tD[3]) << 16);
        *(uint2*)&vT[e1 * 32 + ((16 + 4 * h) ^ ((e1 & 1) << 3))] = p;
      }
    }

    // ---- softmax (fixed-max): P = exp(logit - slope*games_ago), masked -> 0 ----
    {
      float e_[4]; float qs_ = 0.f;
      #pragma unroll
      for (int i = 0; i < 4; ++i){
        int s = s0 + 16 * mt + 4 * h + i;
        float ga = (float)(n_real - 1 - s);
        bool valid = (s < n_real);
        float v = valid ? __expf(as_[i] - slope0 * ga) : 0.f;
        e_[i] = v; qs_ += v;
      }
      float r = qs_ + __shfl_xor(qs_, 16); r += __shfl_xor(r, 32);
      if (l < 16) atomicAdd(&denl[16 * qt + c], r);
      int q = 16 * qt + c;
      int t0 = 16 * mt + 4 * h;
      uint2 p;
      p.x = (unsigned)f2b(e_[0]) | ((unsigned)f2b(e_[1]) << 16);
      p.y = (unsigned)f2b(e_[2]) | ((unsigned)f2b(e_[3]) << 16);
      *(uint2*)&Pl[q * 32 + (t0 ^ ((q & 1) << 3))] = p;
    }
    bar_lgkm();                          // BAR2: vT/Pl visible; K consumed

    // ---- PV over raw keys: ao[q][e] += P[q][t] * K[t][e] ----
    {
      bf16x8_t Ap0 = *(const bf16x8_t*)&Pl[c * 32 + ((8 * h) ^ ((c & 1) << 3))];
      bf16x8_t Ap1 = *(const bf16x8_t*)&Pl[(16 + c) * 32 + ((8 * h) ^ ((c & 1) << 3))];
      #pragma unroll
      for (int nt = 0; nt < 4; ++nt){
        int e = 64 * w + 16 * nt + c;
        bf16x8_t Bv = *(const bf16x8_t*)&vT[e * 32 + ((8 * h) ^ ((e & 1) << 3))];
        ao[0][nt] = MFMA16(Ap0, Bv, ao[0][nt]);
        ao[1][nt] = MFMA16(Ap1, Bv, ao[1][nt]);
      }
    }
  }

  // ---- accumulate partial numerators / denominators (XCD-local lines after swizzle) ----
  #pragma unroll
  for (int q2 = 0; q2 < 2; ++q2)
    #pragma unroll
    for (int nt = 0; nt < 4; ++nt){
      int e = 64 * w + 16 * nt + c;
      #pragma unroll
      for (int i = 0; i < 4; ++i){
        int q = 16 * q2 + 4 * h + i;
        atomicAdd(&acc[((size_t)b * 32 + q) * 256 + e], ao[q2][nt][i]);
      }
    }
  if (tid < 32) atomicAdd(&deng[b * 32 + tid], denl[tid]);
}

// ---------------- epilogue (IN-PLACE on d_out): out[row][e'] = sum_d (out[row][d]/den[row]) * value_w[e'][d] ----------------
__global__ __launch_bounds__(256) void vproj_norm(
    const float* __restrict__ deng, const unsigned short* __restrict__ wvb,
    float* __restrict__ out){
  __shared__ unsigned short at[64 * 256];
  __shared__ float dl[64];
  int tid = threadIdx.x, w = tid >> 6, l = tid & 63, h = l >> 4, c = l & 15;
  size_t r0 = (size_t)blockIdx.x * 64;
  if (tid < 64) dl[tid] = 1.f / deng[r0 + tid];
  __syncthreads();
  #pragma unroll
  for (int j = 0; j < 16; ++j){
    int idx = j * 256 + tid;
    int row = idx >> 6, c4 = (idx & 63) * 4;
    f32x4_t v = *(const f32x4_t*)(out + (r0 + row) * 256 + c4);
    float iv = dl[row];
    uint2 p;
    p.x = (unsigned)f2b(v[0] * iv) | ((unsigned)f2b(v[1] * iv) << 16);
    p.y = (unsigned)f2b(v[2] * iv) | ((unsigned)f2b(v[3] * iv) << 16);
    *(uint2*)&at[row * 256 + (c4 ^ ((row & 7) << 3))] = p;
  }
  __syncthreads();
  f32x4_t zero4 = {0.f, 0.f, 0.f, 0.f};
  f32x4_t a2[4][4];
  #pragma unroll
  for (int m = 0; m < 4; ++m)
    #pragma unroll
    for (int nt = 0; nt < 4; ++nt) a2[m][nt] = zero4;
  #pragma unroll
  for (int kk = 0; kk < 8; ++kk){
    bf16x8_t A[4];
    #pragma unroll
    for (int m = 0; m < 4; ++m){
      int row = c + 16 * m;
      A[m] = *(const bf16x8_t*)&at[row * 256 + ((kk * 32 + 8 * h) ^ ((row & 7) << 3))];
    }
    #pragma unroll
    for (int nt = 0; nt < 4; ++nt){
      int ep = 64 * w + 16 * nt + c;
      bf16x8_t Bv = *(const bf16x8_t*)(wvb + (size_t)ep * 256 + kk * 32 + 8 * h);
      #pragma unroll
      for (int m = 0; m < 4; ++m) a2[m][nt] = MFMA16(A[m], Bv, a2[m][nt]);
    }
  }
  #pragma unroll
  for (int m = 0; m < 4; ++m)
    #pragma unroll
    for (int nt = 0; nt < 4; ++nt)
      #pragma unroll
      for (int i = 0; i < 4; ++i){
        size_t row = r0 + 16 * m + 4 * h + i;
        int ep = 64 * w + 16 * nt + c;
        out[row * 256 + ep] = a2[m][nt][i];
      }
}

extern "C" void kernel_launch(void* const* d_in, const int* in_sizes, int n_in,
                              void* d_out, int out_size, void* d_ws, size_t ws_size,
                              hipStream_t stream){
  const float* keys    = (const float*)d_in[0];
  const int*   mask    = (const int*)d_in[1];
  const float* context = (const float*)d_in[2];
  const float* queries = (const float*)d_in[3];
  const float* key_w   = (const float*)d_in[4];
  const float* value_w = (const float*)d_in[5];
  const float* logt    = (const float*)d_in[6];
  const float* cond_w  = (const float*)d_in[7];
  const float* cond_b  = (const float*)d_in[8];
  float* out = (float*)d_out;

  unsigned short* wkt = (unsigned short*)d_ws;           // 65536 bf16
  unsigned short* wvb = wkt + 65536;                     // 65536 bf16
  unsigned short* qs  = wvb + 65536;                     // 16384*256 bf16
  unsigned short* qkp = qs + (size_t)16384 * 256;        // 16384*256 bf16
  float* deng = (float*)(qkp + (size_t)16384 * 256);     // 16384 f32
  int*   nreal = (int*)(deng + 16384);                   // 512 int

  hipLaunchKernelGGL(setup_k,  dim3(4480), dim3(256), 0, stream, key_w, value_w, mask,
                     (float4*)out, (float4*)deng, wkt, wvb, nreal);
  hipLaunchKernelGGL(calc_qs,  dim3(2048), dim3(256), 0, stream, context, queries, logt, cond_w, cond_b, qs);
  hipLaunchKernelGGL(calc_qkp, dim3(256), dim3(256), 0, stream, qs, wkt, qkp);
  hipLaunchKernelGGL(attn_part, dim3(1024), dim3(256), 0, stream, keys, nreal, qkp, out, deng);
  hipLaunchKernelGGL(vproj_norm, dim3(256), dim3(256), 0, stream, deng, wvb, out);
}